// Round 18
// baseline (133.912 us; speedup 1.0000x reference)
//
#include <hip/hip_runtime.h>
#include <hip/hip_bf16.h>

#define NN 8192
#define DIN 256
#define DOUT 64
#define NCH 8
#define CHJ (NN / NCH)  // 1024

typedef __attribute__((ext_vector_type(4))) float f32x4;
typedef __attribute__((ext_vector_type(4))) int i32x4;
typedef __attribute__((ext_vector_type(8))) short short8;

__device__ __forceinline__ unsigned short f2bf(float f) {
  unsigned u = __float_as_uint(f);
  u += 0x7fffu + ((u >> 16) & 1u);
  return (unsigned short)(u >> 16);
}
__device__ __forceinline__ unsigned pk2bf(float lo, float hi) {
  return (unsigned)f2bf(lo) | ((unsigned)f2bf(hi) << 16);
}
__device__ __forceinline__ unsigned cvtpk(float lo, float hi) {
  unsigned r;
  asm("v_cvt_pk_bf16_f32 %0, %1, %2" : "=v"(r) : "v"(lo), "v"(hi));
  return r;
}

// WTb[d][k] = bf16(W[k][d]); grid 64 x 256
__global__ __launch_bounds__(256) void k_prep(const float* __restrict__ W,
                                              unsigned short* __restrict__ WTb) {
  const int i = blockIdx.x * 256 + threadIdx.x;
  const int d = i >> 8, k = i & 255;
  WTb[i] = f2bf(W[k * DOUT + d]);
}

// h = X@W via MFMA -> src/dst/dmax_arr/HTt. grid 128 x 256.
__global__ __launch_bounds__(256) void k_hw(
    const float* __restrict__ X, const unsigned short* __restrict__ WTb,
    const float* __restrict__ A, float* __restrict__ src,
    float* __restrict__ dst, float* __restrict__ dmax_arr,
    unsigned short* __restrict__ HTt) {
  const int tid = threadIdx.x;
  const int wid = tid >> 6, lane = tid & 63;
  const int l15 = lane & 15, kc = lane >> 4;
  const int rt = blockIdx.x * 64 + wid * 16;
  const float* __restrict__ xr = X + (size_t)(rt + l15) * DIN + kc * 8;
  const unsigned short* __restrict__ wb = WTb + (size_t)l15 * DIN + kc * 8;
  f32x4 acc0 = {0.f, 0.f, 0.f, 0.f};
  f32x4 acc1 = acc0, acc2 = acc0, acc3 = acc0;
#pragma unroll
  for (int ks = 0; ks < 8; ++ks) {
    const f32x4 x0 = *(const f32x4*)(xr + ks * 32);
    const f32x4 x1 = *(const f32x4*)(xr + ks * 32 + 4);
    short8 af;
    ((unsigned*)&af)[0] = pk2bf(x0[0], x0[1]);
    ((unsigned*)&af)[1] = pk2bf(x0[2], x0[3]);
    ((unsigned*)&af)[2] = pk2bf(x1[0], x1[1]);
    ((unsigned*)&af)[3] = pk2bf(x1[2], x1[3]);
    const short8 b0 = *(const short8*)(wb + ks * 32);
    const short8 b1 = *(const short8*)(wb + 16 * DIN + ks * 32);
    const short8 b2 = *(const short8*)(wb + 32 * DIN + ks * 32);
    const short8 b3 = *(const short8*)(wb + 48 * DIN + ks * 32);
    acc0 = __builtin_amdgcn_mfma_f32_16x16x32_bf16(af, b0, acc0, 0, 0, 0);
    acc1 = __builtin_amdgcn_mfma_f32_16x16x32_bf16(af, b1, acc1, 0, 0, 0);
    acc2 = __builtin_amdgcn_mfma_f32_16x16x32_bf16(af, b2, acc2, 0, 0, 0);
    acc3 = __builtin_amdgcn_mfma_f32_16x16x32_bf16(af, b3, acc3, 0, 0, 0);
  }
  const float as0 = A[l15], as1 = A[16 + l15], as2 = A[32 + l15],
              as3 = A[48 + l15];
  const float ad0 = A[64 + l15], ad1 = A[80 + l15], ad2 = A[96 + l15],
              ad3 = A[112 + l15];
  float dm = -1e30f;
#pragma unroll
  for (int v = 0; v < 4; ++v) {
    float sv = acc0[v] * as0 + acc1[v] * as1 + acc2[v] * as2 + acc3[v] * as3;
    float dv = acc0[v] * ad0 + acc1[v] * ad1 + acc2[v] * ad2 + acc3[v] * ad3;
#pragma unroll
    for (int m = 1; m < 16; m <<= 1) {
      sv += __shfl_xor(sv, m);
      dv += __shfl_xor(dv, m);
    }
    if (l15 == 0) {
      src[rt + kc * 4 + v] = sv;
      dst[rt + kc * 4 + v] = dv;
    }
    dm = fmaxf(dm, dv);
  }
  dm = fmaxf(dm, __shfl_xor(dm, 16));
  dm = fmaxf(dm, __shfl_xor(dm, 32));
  if (lane == 0) dmax_arr[blockIdx.x * 4 + wid] = dm;
  // HTt[jb][n][l15][jin] = bf16(h[jb*32+jin][n*16+l15])
  unsigned short* __restrict__ hs =
      HTt + (size_t)(rt >> 5) * 2048 + l15 * 32 + (rt & 16) + kc * 4;
  *(unsigned*)(hs + 0 * 512) = pk2bf(acc0[0], acc0[1]);
  *(unsigned*)(hs + 0 * 512 + 2) = pk2bf(acc0[2], acc0[3]);
  *(unsigned*)(hs + 1 * 512) = pk2bf(acc1[0], acc1[1]);
  *(unsigned*)(hs + 1 * 512 + 2) = pk2bf(acc1[2], acc1[3]);
  *(unsigned*)(hs + 2 * 512) = pk2bf(acc2[0], acc2[1]);
  *(unsigned*)(hs + 2 * 512 + 2) = pk2bf(acc2[2], acc2[3]);
  *(unsigned*)(hs + 3 * 512) = pk2bf(acc3[0], acc3[1]);
  *(unsigned*)(hs + 3 * 512 + 2) = pk2bf(acc3[2], acc3[3]);
}

// Fused adj-stream + masked-softmax-numerator @ H; 32 rows/wave; 4 quarters
// of 256 j. Next quarter's adj loads are pipelined 2-deep (16 i32x4 regs,
// reused) through the current quarter's compute steps.
__global__ __launch_bounds__(256) void k_att(
    const int* __restrict__ adj, const float* __restrict__ src,
    const float* __restrict__ dst, const float* __restrict__ dmax_arr,
    const unsigned short* __restrict__ HTt, float* __restrict__ pacc,
    float* __restrict__ ps) {
  __shared__ float E1s[CHJ], E2s[CHJ];
  __shared__ float dsm[4];
  __shared__ unsigned short Hs[16384];  // 32 KB: [8 s][4 n][64 lane][8]
  const int tid = threadIdx.x;
  const int wid = tid >> 6, lane = tid & 63;
  const int l15 = lane & 15, kc = lane >> 4;
  const int rowtile = blockIdx.x * 128 + wid * 32;
  const int c = blockIdx.y;
  const int cbase = c * CHJ;
  const int hfirst = (blockIdx.x + blockIdx.y) & 3;  // 4-phase stagger
  const int* __restrict__ abase = adj + (size_t)rowtile * NN + cbase + lane * 4;
  i32x4 vb0[8], vb1[8];  // 2-deep in-flight buffers (reused per half)
  unsigned long long nwA64[4] = {0ull, 0ull, 0ull, 0ull};
  unsigned long long nwB64[4] = {0ull, 0ull, 0ull, 0ull};
  unsigned loA[4], hiA[4], loB[4], hiB[4];

#define ISSUE8(VB, G, H)                                                     \
  do {                                                                       \
    _Pragma("unroll") for (int r8 = 0; r8 < 8; ++r8) VB[r8] =                \
        *(const i32x4*)(abase + (size_t)((G) * 8 + r8) * NN + (H) * 256);    \
  } while (0)

#define BALLOT8(VB, G)                                                       \
  do {                                                                       \
    _Pragma("unroll") for (int r8 = 0; r8 < 8; ++r8) {                       \
      const int rr = (G) * 8 + r8;                                           \
      const unsigned long long b0 = __ballot(VB[r8][0] > 0);                 \
      const unsigned long long b1 = __ballot(VB[r8][1] > 0);                 \
      const unsigned long long b2 = __ballot(VB[r8][2] > 0);                 \
      const unsigned long long b3 = __ballot(VB[r8][3] > 0);                 \
      if ((G) < 2) {                                                         \
        const bool isA = (l15 == rr);                                        \
        nwA64[0] = isA ? b0 : nwA64[0];                                      \
        nwA64[1] = isA ? b1 : nwA64[1];                                      \
        nwA64[2] = isA ? b2 : nwA64[2];                                      \
        nwA64[3] = isA ? b3 : nwA64[3];                                      \
      } else {                                                               \
        const bool isB = (l15 == rr - 16);                                   \
        nwB64[0] = isB ? b0 : nwB64[0];                                      \
        nwB64[1] = isB ? b1 : nwB64[1];                                      \
        nwB64[2] = isB ? b2 : nwB64[2];                                      \
        nwB64[3] = isB ? b3 : nwB64[3];                                      \
      }                                                                      \
    }                                                                        \
  } while (0)

#define SHIFTMASKS                                                           \
  do {                                                                       \
    _Pragma("unroll") for (int m = 0; m < 4; ++m) {                          \
      const unsigned long long shA = nwA64[m] >> (kc * 2);                   \
      const unsigned long long shB = nwB64[m] >> (kc * 2);                   \
      loA[m] = (unsigned)shA;                                                \
      hiA[m] = (unsigned)(shA >> 32);                                        \
      loB[m] = (unsigned)shB;                                                \
      hiB[m] = (unsigned)(shB >> 32);                                        \
    }                                                                        \
  } while (0)

  // prologue pack of quarter hfirst, 2-deep, overlapped with setup
  ISSUE8(vb0, 0, hfirst);
  ISSUE8(vb1, 1, hfirst);
  {
    const f32x4 dv4 = *(const f32x4*)(dst + cbase + tid * 4);
    E1s[tid * 4 + 0] = __expf(dv4[0]);
    E1s[tid * 4 + 1] = __expf(dv4[1]);
    E1s[tid * 4 + 2] = __expf(dv4[2]);
    E1s[tid * 4 + 3] = __expf(dv4[3]);
    E2s[tid * 4 + 0] = __expf(0.2f * dv4[0]);
    E2s[tid * 4 + 1] = __expf(0.2f * dv4[1]);
    E2s[tid * 4 + 2] = __expf(0.2f * dv4[2]);
    E2s[tid * 4 + 3] = __expf(0.2f * dv4[3]);
    float dm0 = fmaxf(dmax_arr[tid], dmax_arr[tid + 256]);
#pragma unroll
    for (int m = 1; m < 64; m <<= 1) dm0 = fmaxf(dm0, __shfl_xor(dm0, m));
    if (lane == 0) dsm[wid] = dm0;
  }
  __syncthreads();
  BALLOT8(vb0, 0);
  BALLOT8(vb1, 1);
  ISSUE8(vb0, 2, hfirst);
  ISSUE8(vb1, 3, hfirst);
  const float dmx = fmaxf(fmaxf(dsm[0], dsm[1]), fmaxf(dsm[2], dsm[3]));
  const int arA = rowtile + l15, arB = arA + 16;
  const float sA = src[arA], sB = src[arB];
  const float eA = sA + dmx, eB = sB + dmx;
  const float miA = fmaxf(eA, 0.2f * eA), miB = fmaxf(eB, 0.2f * eB);
  const float cA1 = __expf(sA - miA), cA2 = __expf(0.2f * sA - miA);
  const float cB1 = __expf(sB - miB), cB2 = __expf(0.2f * sB - miB);
  BALLOT8(vb0, 2);
  BALLOT8(vb1, 3);
  SHIFTMASKS;
  f32x4 aA0 = {0.f, 0.f, 0.f, 0.f};
  f32x4 aA1 = aA0, aA2 = aA0, aA3 = aA0;
  f32x4 aB0 = aA0, aB1 = aA0, aB2 = aA0, aB3 = aA0;
  float sacA = 0.f, sacB = 0.f;
  // staging source: permute [s][n][l15][kc*8] -> lds [s][n][lane][8]
  const unsigned short* __restrict__ Hsrc =
      HTt + (size_t)(cbase >> 5) * 2048 + (tid >> 6) * 512 + (tid & 15) * 32 +
      ((tid >> 4) & 3) * 8;
  const int HsW = (tid >> 6) * 512 + (tid & 63) * 8;  // dst short idx (per s)

  auto cstep = [&](int h, int q, int s4) {
    const int sl = q * 4 + s4;  // s_local in quarter
    const int jr = (h * 8 + sl) * 32 + kc * 8;
    const f32x4 e1a = *(const f32x4*)&E1s[jr];
    const f32x4 e1b = *(const f32x4*)&E1s[jr + 4];
    const f32x4 e2a = *(const f32x4*)&E2s[jr];
    const f32x4 e2b = *(const f32x4*)&E2s[jr + 4];
    float pvA[8], pvB[8];
#pragma unroll
    for (int e = 0; e < 8; ++e) {
      const float E1v = (e < 4) ? e1a[e & 3] : e1b[e & 3];
      const float E2v = (e < 4) ? e2a[e & 3] : e2b[e & 3];
      const unsigned bsh = s4 * 8 + (e >> 2);
      const unsigned wa = q ? hiA[e & 3] : loA[e & 3];
      const unsigned wb2 = q ? hiB[e & 3] : loB[e & 3];
      float pA = fmaxf(cA1 * E1v, cA2 * E2v);
      float pB = fmaxf(cB1 * E1v, cB2 * E2v);
      pA = ((wa >> bsh) & 1u) ? pA : 0.f;
      pB = ((wb2 >> bsh) & 1u) ? pB : 0.f;
      sacA += pA;
      sacB += pB;
      pvA[e] = pA;
      pvB[e] = pB;
    }
    short8 afA, afB;
    ((unsigned*)&afA)[0] = cvtpk(pvA[0], pvA[1]);
    ((unsigned*)&afA)[1] = cvtpk(pvA[2], pvA[3]);
    ((unsigned*)&afA)[2] = cvtpk(pvA[4], pvA[5]);
    ((unsigned*)&afA)[3] = cvtpk(pvA[6], pvA[7]);
    ((unsigned*)&afB)[0] = cvtpk(pvB[0], pvB[1]);
    ((unsigned*)&afB)[1] = cvtpk(pvB[2], pvB[3]);
    ((unsigned*)&afB)[2] = cvtpk(pvB[4], pvB[5]);
    ((unsigned*)&afB)[3] = cvtpk(pvB[6], pvB[7]);
    const unsigned short* hj = Hs + sl * 2048 + lane * 8;
    const short8 bf0 = *(const short8*)(hj);
    const short8 bf1 = *(const short8*)(hj + 512);
    const short8 bf2 = *(const short8*)(hj + 1024);
    const short8 bf3 = *(const short8*)(hj + 1536);
    aA0 = __builtin_amdgcn_mfma_f32_16x16x32_bf16(afA, bf0, aA0, 0, 0, 0);
    aB0 = __builtin_amdgcn_mfma_f32_16x16x32_bf16(afB, bf0, aB0, 0, 0, 0);
    aA1 = __builtin_amdgcn_mfma_f32_16x16x32_bf16(afA, bf1, aA1, 0, 0, 0);
    aB1 = __builtin_amdgcn_mfma_f32_16x16x32_bf16(afB, bf1, aB1, 0, 0, 0);
    aA2 = __builtin_amdgcn_mfma_f32_16x16x32_bf16(afA, bf2, aA2, 0, 0, 0);
    aB2 = __builtin_amdgcn_mfma_f32_16x16x32_bf16(afB, bf2, aB2, 0, 0, 0);
    aA3 = __builtin_amdgcn_mfma_f32_16x16x32_bf16(afA, bf3, aA3, 0, 0, 0);
    aB3 = __builtin_amdgcn_mfma_f32_16x16x32_bf16(afB, bf3, aB3, 0, 0, 0);
  };

  for (int hh = 0; hh < 4; ++hh) {
    const int h = (hfirst + hh) & 3;
    const int hn = (hfirst + hh + 1) & 3;
    if (hh) __syncthreads();  // protect Hs before overwrite
#pragma unroll
    for (int it = 0; it < 8; ++it) {
      const short8 v = *(const short8*)(Hsrc + (h * 8 + it) * 2048);
      *(short8*)(Hs + it * 2048 + HsW) = v;
    }
    __syncthreads();
    if (hh < 3) {
      // 2-deep: 16 loads fly over 4 compute steps, ballot, repeat
      ISSUE8(vb0, 0, hn);
      ISSUE8(vb1, 1, hn);
      cstep(h, 0, 0);
      cstep(h, 0, 1);
      cstep(h, 0, 2);
      cstep(h, 0, 3);
      BALLOT8(vb0, 0);
      BALLOT8(vb1, 1);
      ISSUE8(vb0, 2, hn);
      ISSUE8(vb1, 3, hn);
      cstep(h, 1, 0);
      cstep(h, 1, 1);
      cstep(h, 1, 2);
      cstep(h, 1, 3);
      BALLOT8(vb0, 2);
      BALLOT8(vb1, 3);
      SHIFTMASKS;
    } else {
#pragma unroll
      for (int q = 0; q < 2; ++q)
#pragma unroll
        for (int s4 = 0; s4 < 4; ++s4) cstep(h, q, s4);
    }
  }
#undef ISSUE8
#undef BALLOT8
#undef SHIFTMASKS

  float stA = sacA, stB = sacB;
  stA += __shfl_xor(stA, 16);
  stA += __shfl_xor(stA, 32);
  stB += __shfl_xor(stB, 16);
  stB += __shfl_xor(stB, 32);
  if (lane < 16) {
    ps[(size_t)c * NN + arA] = stA;
    ps[(size_t)c * NN + arB] = stB;
  }
  const int orA = rowtile + kc * 4;  // C/D: col=lane&15, row=kc*4+v
  float* __restrict__ pbA = pacc + ((size_t)c * NN + orA) * DOUT + l15;
  float* __restrict__ pbB = pbA + (size_t)16 * DOUT;
#pragma unroll
  for (int v = 0; v < 4; ++v) {
    pbA[(size_t)v * DOUT + 0] = aA0[v];
    pbA[(size_t)v * DOUT + 16] = aA1[v];
    pbA[(size_t)v * DOUT + 32] = aA2[v];
    pbA[(size_t)v * DOUT + 48] = aA3[v];
    pbB[(size_t)v * DOUT + 0] = aB0[v];
    pbB[(size_t)v * DOUT + 16] = aB1[v];
    pbB[(size_t)v * DOUT + 32] = aB2[v];
    pbB[(size_t)v * DOUT + 48] = aB3[v];
  }
}

__global__ __launch_bounds__(256) void k_fin(const float* __restrict__ pacc,
                                             const float* __restrict__ ps,
                                             float* __restrict__ out) {
  const int idx4 = blockIdx.x * 256 + threadIdx.x;  // float4 index
  const int i = idx4 >> 4;
  float ss = 0.f;
  f32x4 as = {0.f, 0.f, 0.f, 0.f};
  const f32x4* __restrict__ p4 = (const f32x4*)pacc;
#pragma unroll
  for (int c = 0; c < NCH; ++c) {
    ss += ps[(size_t)c * NN + i];
    const f32x4 v = p4[(size_t)c * (NN * DOUT / 4) + idx4];
    as[0] += v[0];
    as[1] += v[1];
    as[2] += v[2];
    as[3] += v[3];
  }
  const float inv = 1.f / ss;
  f32x4 o;
#pragma unroll
  for (int e = 0; e < 4; ++e) {
    const float v = as[e] * inv;
    o[e] = v > 0.f ? v : (__expf(v) - 1.f);
  }
  *(f32x4*)(out + (size_t)idx4 * 4) = o;
}

extern "C" void kernel_launch(void* const* d_in, const int* in_sizes, int n_in,
                              void* d_out, int out_size, void* d_ws,
                              size_t ws_size, hipStream_t stream) {
  const float* X = (const float*)d_in[0];
  const int* adj = (const int*)d_in[1];
  const float* W = (const float*)d_in[2];
  const float* A = (const float*)d_in[3];
  float* out = (float*)d_out;
  char* ws = (char*)d_ws;
  float* src = (float*)(ws);                                   // 32 KB
  float* dst = (float*)(ws + (32u << 10));                     // 32 KB
  float* dmax_arr = (float*)(ws + (64u << 10));                // 2 KB
  unsigned short* WTb = (unsigned short*)(ws + (128u << 10));  // 32 KB
  unsigned short* HTt = (unsigned short*)(ws + (256u << 10));  // 1 MB
  float* pacc = (float*)(ws + (16u << 20));    // NCH*2 MB = 16 MB
  float* ps = pacc + (size_t)NCH * NN * DOUT;  // NCH*32 KB
  k_prep<<<64, 256, 0, stream>>>(W, WTb);
  k_hw<<<NN / 64, 256, 0, stream>>>(X, WTb, A, src, dst, dmax_arr, HTt);
  k_att<<<dim3(NN / 128, NCH), 256, 0, stream>>>(adj, src, dst, dmax_arr, HTt,
                                                 pacc, ps);
  k_fin<<<NN * DOUT / 1024, 256, 0, stream>>>(pacc, ps, out);
}

// Round 19
// 73.100 us; speedup vs baseline: 1.8319x; 1.8319x over previous
//
#include <hip/hip_runtime.h>
#include <hip/hip_bf16.h>

#define NN 8192
#define DIN 256
#define DOUT 64
#define NCH 8
#define CHJ (NN / NCH)  // 1024

typedef __attribute__((ext_vector_type(4))) float f32x4;
typedef __attribute__((ext_vector_type(4))) int i32x4;
typedef __attribute__((ext_vector_type(8))) short short8;
typedef __attribute__((ext_vector_type(4))) unsigned short u16x4;

__device__ __forceinline__ unsigned short f2bf(float f) {
  unsigned u = __float_as_uint(f);
  u += 0x7fffu + ((u >> 16) & 1u);
  return (unsigned short)(u >> 16);
}
__device__ __forceinline__ unsigned pk2bf(float lo, float hi) {
  return (unsigned)f2bf(lo) | ((unsigned)f2bf(hi) << 16);
}
__device__ __forceinline__ float bf2f(unsigned short s) {
  return __uint_as_float((unsigned)s << 16);
}
__device__ __forceinline__ unsigned cvtpk(float lo, float hi) {
  unsigned r;
  asm("v_cvt_pk_bf16_f32 %0, %1, %2" : "=v"(r) : "v"(lo), "v"(hi));
  return r;
}

// WTb[d][k] = bf16(W[k][d]); grid 64 x 256
__global__ __launch_bounds__(256) void k_prep(const float* __restrict__ W,
                                              unsigned short* __restrict__ WTb) {
  const int i = blockIdx.x * 256 + threadIdx.x;
  const int d = i >> 8, k = i & 255;
  WTb[i] = f2bf(W[k * DOUT + d]);
}

// h = X@W via MFMA -> src/dst/dmax_arr/HTt. grid 128 x 256.
__global__ __launch_bounds__(256) void k_hw(
    const float* __restrict__ X, const unsigned short* __restrict__ WTb,
    const float* __restrict__ A, float* __restrict__ src,
    float* __restrict__ dst, float* __restrict__ dmax_arr,
    unsigned short* __restrict__ HTt) {
  const int tid = threadIdx.x;
  const int wid = tid >> 6, lane = tid & 63;
  const int l15 = lane & 15, kc = lane >> 4;
  const int rt = blockIdx.x * 64 + wid * 16;
  const float* __restrict__ xr = X + (size_t)(rt + l15) * DIN + kc * 8;
  const unsigned short* __restrict__ wb = WTb + (size_t)l15 * DIN + kc * 8;
  f32x4 acc0 = {0.f, 0.f, 0.f, 0.f};
  f32x4 acc1 = acc0, acc2 = acc0, acc3 = acc0;
#pragma unroll
  for (int ks = 0; ks < 8; ++ks) {
    const f32x4 x0 = *(const f32x4*)(xr + ks * 32);
    const f32x4 x1 = *(const f32x4*)(xr + ks * 32 + 4);
    short8 af;
    ((unsigned*)&af)[0] = pk2bf(x0[0], x0[1]);
    ((unsigned*)&af)[1] = pk2bf(x0[2], x0[3]);
    ((unsigned*)&af)[2] = pk2bf(x1[0], x1[1]);
    ((unsigned*)&af)[3] = pk2bf(x1[2], x1[3]);
    const short8 b0 = *(const short8*)(wb + ks * 32);
    const short8 b1 = *(const short8*)(wb + 16 * DIN + ks * 32);
    const short8 b2 = *(const short8*)(wb + 32 * DIN + ks * 32);
    const short8 b3 = *(const short8*)(wb + 48 * DIN + ks * 32);
    acc0 = __builtin_amdgcn_mfma_f32_16x16x32_bf16(af, b0, acc0, 0, 0, 0);
    acc1 = __builtin_amdgcn_mfma_f32_16x16x32_bf16(af, b1, acc1, 0, 0, 0);
    acc2 = __builtin_amdgcn_mfma_f32_16x16x32_bf16(af, b2, acc2, 0, 0, 0);
    acc3 = __builtin_amdgcn_mfma_f32_16x16x32_bf16(af, b3, acc3, 0, 0, 0);
  }
  const float as0 = A[l15], as1 = A[16 + l15], as2 = A[32 + l15],
              as3 = A[48 + l15];
  const float ad0 = A[64 + l15], ad1 = A[80 + l15], ad2 = A[96 + l15],
              ad3 = A[112 + l15];
  float dm = -1e30f;
#pragma unroll
  for (int v = 0; v < 4; ++v) {
    float sv = acc0[v] * as0 + acc1[v] * as1 + acc2[v] * as2 + acc3[v] * as3;
    float dv = acc0[v] * ad0 + acc1[v] * ad1 + acc2[v] * ad2 + acc3[v] * ad3;
#pragma unroll
    for (int m = 1; m < 16; m <<= 1) {
      sv += __shfl_xor(sv, m);
      dv += __shfl_xor(dv, m);
    }
    if (l15 == 0) {
      src[rt + kc * 4 + v] = sv;
      dst[rt + kc * 4 + v] = dv;
    }
    dm = fmaxf(dm, dv);
  }
  dm = fmaxf(dm, __shfl_xor(dm, 16));
  dm = fmaxf(dm, __shfl_xor(dm, 32));
  if (lane == 0) dmax_arr[blockIdx.x * 4 + wid] = dm;
  // HTt[jb][n][l15][jin] = bf16(h[jb*32+jin][n*16+l15])
  unsigned short* __restrict__ hs =
      HTt + (size_t)(rt >> 5) * 2048 + l15 * 32 + (rt & 16) + kc * 4;
  *(unsigned*)(hs + 0 * 512) = pk2bf(acc0[0], acc0[1]);
  *(unsigned*)(hs + 0 * 512 + 2) = pk2bf(acc0[2], acc0[3]);
  *(unsigned*)(hs + 1 * 512) = pk2bf(acc1[0], acc1[1]);
  *(unsigned*)(hs + 1 * 512 + 2) = pk2bf(acc1[2], acc1[3]);
  *(unsigned*)(hs + 2 * 512) = pk2bf(acc2[0], acc2[1]);
  *(unsigned*)(hs + 2 * 512 + 2) = pk2bf(acc2[2], acc2[3]);
  *(unsigned*)(hs + 3 * 512) = pk2bf(acc3[0], acc3[1]);
  *(unsigned*)(hs + 3 * 512 + 2) = pk2bf(acc3[2], acc3[3]);
}

// Fused adj-stream + masked-softmax-numerator @ H via MFMA; 32 rows/wave.
// 4 quarters of 256 j; quarter order staggered; bf16 partial output.
__global__ __launch_bounds__(256) void k_att(
    const int* __restrict__ adj, const float* __restrict__ src,
    const float* __restrict__ dst, const float* __restrict__ dmax_arr,
    const unsigned short* __restrict__ HTt, unsigned short* __restrict__ pacc,
    float* __restrict__ ps) {
  __shared__ float E1s[CHJ], E2s[CHJ];
  __shared__ float dsm[4];
  __shared__ unsigned short Hs[16384];  // 32 KB: [8 s][4 n][64 lane][8]
  const int tid = threadIdx.x;
  const int wid = tid >> 6, lane = tid & 63;
  const int l15 = lane & 15, kc = lane >> 4;
  const int rowtile = blockIdx.x * 128 + wid * 32;
  const int c = blockIdx.y;
  const int cbase = c * CHJ;
  {
    const f32x4 dv4 = *(const f32x4*)(dst + cbase + tid * 4);
    E1s[tid * 4 + 0] = __expf(dv4[0]);
    E1s[tid * 4 + 1] = __expf(dv4[1]);
    E1s[tid * 4 + 2] = __expf(dv4[2]);
    E1s[tid * 4 + 3] = __expf(dv4[3]);
    E2s[tid * 4 + 0] = __expf(0.2f * dv4[0]);
    E2s[tid * 4 + 1] = __expf(0.2f * dv4[1]);
    E2s[tid * 4 + 2] = __expf(0.2f * dv4[2]);
    E2s[tid * 4 + 3] = __expf(0.2f * dv4[3]);
    float dm0 = fmaxf(dmax_arr[tid], dmax_arr[tid + 256]);
#pragma unroll
    for (int m = 1; m < 64; m <<= 1) dm0 = fmaxf(dm0, __shfl_xor(dm0, m));
    if (lane == 0) dsm[wid] = dm0;
  }
  __syncthreads();
  const float dmx = fmaxf(fmaxf(dsm[0], dsm[1]), fmaxf(dsm[2], dsm[3]));
  const int arA = rowtile + l15, arB = arA + 16;
  const float sA = src[arA], sB = src[arB];
  const float eA = sA + dmx, eB = sB + dmx;
  const float miA = fmaxf(eA, 0.2f * eA), miB = fmaxf(eB, 0.2f * eB);
  const float cA1 = __expf(sA - miA), cA2 = __expf(0.2f * sA - miA);
  const float cB1 = __expf(sB - miB), cB2 = __expf(0.2f * sB - miB);
  f32x4 aA0 = {0.f, 0.f, 0.f, 0.f};
  f32x4 aA1 = aA0, aA2 = aA0, aA3 = aA0;
  f32x4 aB0 = aA0, aB1 = aA0, aB2 = aA0, aB3 = aA0;
  float sacA = 0.f, sacB = 0.f;
  // staging source: permute [s][n][l15][kc*8] -> lds [s][n][lane][8]
  const unsigned short* __restrict__ Hsrc =
      HTt + (size_t)(cbase >> 5) * 2048 + (tid >> 6) * 512 + (tid & 15) * 32 +
      ((tid >> 4) & 3) * 8;
  const int HsW = (tid >> 6) * 512 + (tid & 63) * 8;  // dst short idx (per s)
  const int hfirst = (blockIdx.x + blockIdx.y) & 3;   // 4-phase stagger
#pragma unroll
  for (int hh = 0; hh < 4; ++hh) {
    const int h = (hfirst + hh) & 3;
    // ---- inline pack of this wave's 32 rows for this 256-j quarter ----
    unsigned loA[4], hiA[4], loB[4], hiB[4];
    {
      unsigned long long wA64[4] = {0ull, 0ull, 0ull, 0ull};
      unsigned long long wB64[4] = {0ull, 0ull, 0ull, 0ull};
      const int* __restrict__ ab =
          adj + (size_t)rowtile * NN + cbase + h * 256 + lane * 4;
#pragma unroll
      for (int g = 0; g < 4; ++g) {
        i32x4 v[8];
#pragma unroll
        for (int r8 = 0; r8 < 8; ++r8)
          v[r8] = *(const i32x4*)(ab + (size_t)(g * 8 + r8) * NN);
#pragma unroll
        for (int r8 = 0; r8 < 8; ++r8) {
          const int rr = g * 8 + r8;
          const unsigned long long b0 = __ballot(v[r8][0] > 0);
          const unsigned long long b1 = __ballot(v[r8][1] > 0);
          const unsigned long long b2 = __ballot(v[r8][2] > 0);
          const unsigned long long b3 = __ballot(v[r8][3] > 0);
          if (rr < 16) {
            const bool isA = (l15 == rr);
            wA64[0] = isA ? b0 : wA64[0];
            wA64[1] = isA ? b1 : wA64[1];
            wA64[2] = isA ? b2 : wA64[2];
            wA64[3] = isA ? b3 : wA64[3];
          } else {
            const bool isB = (l15 == rr - 16);
            wB64[0] = isB ? b0 : wB64[0];
            wB64[1] = isB ? b1 : wB64[1];
            wB64[2] = isB ? b2 : wB64[2];
            wB64[3] = isB ? b3 : wB64[3];
          }
        }
      }
#pragma unroll
      for (int m = 0; m < 4; ++m) {
        const unsigned long long shA = wA64[m] >> (kc * 2);
        const unsigned long long shB = wB64[m] >> (kc * 2);
        loA[m] = (unsigned)shA;
        hiA[m] = (unsigned)(shA >> 32);
        loB[m] = (unsigned)shB;
        hiB[m] = (unsigned)(shB >> 32);
      }
    }
    if (hh) __syncthreads();  // protect Hs before overwrite
    // stage 32KB quarter: s_local 0..7; thread copies one short8 per s_local
#pragma unroll
    for (int it = 0; it < 8; ++it) {
      const short8 v = *(const short8*)(Hsrc + (h * 8 + it) * 2048);
      *(short8*)(Hs + it * 2048 + HsW) = v;
    }
    __syncthreads();
#pragma unroll
    for (int q = 0; q < 2; ++q) {
#pragma unroll 2
      for (int s4 = 0; s4 < 4; ++s4) {
        const int sl = q * 4 + s4;  // s_local in quarter
        const int jr = (h * 8 + sl) * 32 + kc * 8;
        const f32x4 e1a = *(const f32x4*)&E1s[jr];
        const f32x4 e1b = *(const f32x4*)&E1s[jr + 4];
        const f32x4 e2a = *(const f32x4*)&E2s[jr];
        const f32x4 e2b = *(const f32x4*)&E2s[jr + 4];
        float pvA[8], pvB[8];
#pragma unroll
        for (int e = 0; e < 8; ++e) {
          const float E1v = (e < 4) ? e1a[e & 3] : e1b[e & 3];
          const float E2v = (e < 4) ? e2a[e & 3] : e2b[e & 3];
          const unsigned bsh = s4 * 8 + (e >> 2);
          const unsigned wa = q ? hiA[e & 3] : loA[e & 3];
          const unsigned wb2 = q ? hiB[e & 3] : loB[e & 3];
          float pA = fmaxf(cA1 * E1v, cA2 * E2v);
          float pB = fmaxf(cB1 * E1v, cB2 * E2v);
          pA = ((wa >> bsh) & 1u) ? pA : 0.f;
          pB = ((wb2 >> bsh) & 1u) ? pB : 0.f;
          sacA += pA;
          sacB += pB;
          pvA[e] = pA;
          pvB[e] = pB;
        }
        short8 afA, afB;
        ((unsigned*)&afA)[0] = cvtpk(pvA[0], pvA[1]);
        ((unsigned*)&afA)[1] = cvtpk(pvA[2], pvA[3]);
        ((unsigned*)&afA)[2] = cvtpk(pvA[4], pvA[5]);
        ((unsigned*)&afA)[3] = cvtpk(pvA[6], pvA[7]);
        ((unsigned*)&afB)[0] = cvtpk(pvB[0], pvB[1]);
        ((unsigned*)&afB)[1] = cvtpk(pvB[2], pvB[3]);
        ((unsigned*)&afB)[2] = cvtpk(pvB[4], pvB[5]);
        ((unsigned*)&afB)[3] = cvtpk(pvB[6], pvB[7]);
        const unsigned short* hj = Hs + sl * 2048 + lane * 8;
        const short8 bf0 = *(const short8*)(hj);
        const short8 bf1 = *(const short8*)(hj + 512);
        const short8 bf2 = *(const short8*)(hj + 1024);
        const short8 bf3 = *(const short8*)(hj + 1536);
        aA0 = __builtin_amdgcn_mfma_f32_16x16x32_bf16(afA, bf0, aA0, 0, 0, 0);
        aB0 = __builtin_amdgcn_mfma_f32_16x16x32_bf16(afB, bf0, aB0, 0, 0, 0);
        aA1 = __builtin_amdgcn_mfma_f32_16x16x32_bf16(afA, bf1, aA1, 0, 0, 0);
        aB1 = __builtin_amdgcn_mfma_f32_16x16x32_bf16(afB, bf1, aB1, 0, 0, 0);
        aA2 = __builtin_amdgcn_mfma_f32_16x16x32_bf16(afA, bf2, aA2, 0, 0, 0);
        aB2 = __builtin_amdgcn_mfma_f32_16x16x32_bf16(afB, bf2, aB2, 0, 0, 0);
        aA3 = __builtin_amdgcn_mfma_f32_16x16x32_bf16(afA, bf3, aA3, 0, 0, 0);
        aB3 = __builtin_amdgcn_mfma_f32_16x16x32_bf16(afB, bf3, aB3, 0, 0, 0);
      }
    }
  }
  float stA = sacA, stB = sacB;
  stA += __shfl_xor(stA, 16);
  stA += __shfl_xor(stA, 32);
  stB += __shfl_xor(stB, 16);
  stB += __shfl_xor(stB, 32);
  if (lane < 16) {
    ps[(size_t)c * NN + arA] = stA;
    ps[(size_t)c * NN + arB] = stB;
  }
  const int orA = rowtile + kc * 4;  // C/D: col=lane&15, row=kc*4+v
  unsigned short* __restrict__ pbA =
      pacc + ((size_t)c * NN + orA) * DOUT + l15;
  unsigned short* __restrict__ pbB = pbA + (size_t)16 * DOUT;
#pragma unroll
  for (int v = 0; v < 4; ++v) {
    pbA[(size_t)v * DOUT + 0] = f2bf(aA0[v]);
    pbA[(size_t)v * DOUT + 16] = f2bf(aA1[v]);
    pbA[(size_t)v * DOUT + 32] = f2bf(aA2[v]);
    pbA[(size_t)v * DOUT + 48] = f2bf(aA3[v]);
    pbB[(size_t)v * DOUT + 0] = f2bf(aB0[v]);
    pbB[(size_t)v * DOUT + 16] = f2bf(aB1[v]);
    pbB[(size_t)v * DOUT + 32] = f2bf(aB2[v]);
    pbB[(size_t)v * DOUT + 48] = f2bf(aB3[v]);
  }
}

__global__ __launch_bounds__(256) void k_fin(
    const unsigned short* __restrict__ pacc, const float* __restrict__ ps,
    float* __restrict__ out) {
  const int idx4 = blockIdx.x * 256 + threadIdx.x;  // group-of-4 index
  const int i = idx4 >> 4;
  float ss = 0.f;
  f32x4 as = {0.f, 0.f, 0.f, 0.f};
  const u16x4* __restrict__ p4 = (const u16x4*)pacc;
#pragma unroll
  for (int c = 0; c < NCH; ++c) {
    ss += ps[(size_t)c * NN + i];
    const u16x4 v = p4[(size_t)c * (NN * DOUT / 4) + idx4];
    as[0] += bf2f(v[0]);
    as[1] += bf2f(v[1]);
    as[2] += bf2f(v[2]);
    as[3] += bf2f(v[3]);
  }
  const float inv = 1.f / ss;
  f32x4 o;
#pragma unroll
  for (int e = 0; e < 4; ++e) {
    const float v = as[e] * inv;
    o[e] = v > 0.f ? v : (__expf(v) - 1.f);
  }
  *(f32x4*)(out + (size_t)idx4 * 4) = o;
}

extern "C" void kernel_launch(void* const* d_in, const int* in_sizes, int n_in,
                              void* d_out, int out_size, void* d_ws,
                              size_t ws_size, hipStream_t stream) {
  const float* X = (const float*)d_in[0];
  const int* adj = (const int*)d_in[1];
  const float* W = (const float*)d_in[2];
  const float* A = (const float*)d_in[3];
  float* out = (float*)d_out;
  char* ws = (char*)d_ws;
  float* src = (float*)(ws);                                   // 32 KB
  float* dst = (float*)(ws + (32u << 10));                     // 32 KB
  float* dmax_arr = (float*)(ws + (64u << 10));                // 2 KB
  unsigned short* WTb = (unsigned short*)(ws + (128u << 10));  // 32 KB
  unsigned short* HTt = (unsigned short*)(ws + (256u << 10));  // 1 MB
  unsigned short* pacc = (unsigned short*)(ws + (16u << 20));  // NCH*1 MB=8 MB
  float* ps = (float*)(ws + (16u << 20) +
                       (size_t)NCH * NN * DOUT * sizeof(unsigned short));
  k_prep<<<64, 256, 0, stream>>>(W, WTb);
  k_hw<<<NN / 64, 256, 0, stream>>>(X, WTb, A, src, dst, dmax_arr, HTt);
  k_att<<<dim3(NN / 128, NCH), 256, 0, stream>>>(adj, src, dst, dmax_arr, HTt,
                                                 pacc, ps);
  k_fin<<<NN * DOUT / 1024, 256, 0, stream>>>(pacc, ps, out);
}

// Round 20
// 72.382 us; speedup vs baseline: 1.8501x; 1.0099x over previous
//
#include <hip/hip_runtime.h>
#include <hip/hip_bf16.h>

#define NN 8192
#define DIN 256
#define DOUT 64
#define NCH 16
#define CHJ (NN / NCH)  // 512

typedef __attribute__((ext_vector_type(4))) float f32x4;
typedef __attribute__((ext_vector_type(4))) int i32x4;
typedef __attribute__((ext_vector_type(8))) short short8;
typedef __attribute__((ext_vector_type(4))) unsigned short u16x4;

__device__ __forceinline__ unsigned short f2bf(float f) {
  unsigned u = __float_as_uint(f);
  u += 0x7fffu + ((u >> 16) & 1u);
  return (unsigned short)(u >> 16);
}
__device__ __forceinline__ unsigned pk2bf(float lo, float hi) {
  return (unsigned)f2bf(lo) | ((unsigned)f2bf(hi) << 16);
}
__device__ __forceinline__ float bf2f(unsigned short s) {
  return __uint_as_float((unsigned)s << 16);
}
__device__ __forceinline__ unsigned cvtpk(float lo, float hi) {
  unsigned r;
  asm("v_cvt_pk_bf16_f32 %0, %1, %2" : "=v"(r) : "v"(lo), "v"(hi));
  return r;
}

// WTb[d][k] = bf16(W[k][d]); grid 64 x 256
__global__ __launch_bounds__(256) void k_prep(const float* __restrict__ W,
                                              unsigned short* __restrict__ WTb) {
  const int i = blockIdx.x * 256 + threadIdx.x;
  const int d = i >> 8, k = i & 255;
  WTb[i] = f2bf(W[k * DOUT + d]);
}

// h = X@W via MFMA -> src/dst/dmax_arr/HTt. grid 128 x 256.
__global__ __launch_bounds__(256) void k_hw(
    const float* __restrict__ X, const unsigned short* __restrict__ WTb,
    const float* __restrict__ A, float* __restrict__ src,
    float* __restrict__ dst, float* __restrict__ dmax_arr,
    unsigned short* __restrict__ HTt) {
  const int tid = threadIdx.x;
  const int wid = tid >> 6, lane = tid & 63;
  const int l15 = lane & 15, kc = lane >> 4;
  const int rt = blockIdx.x * 64 + wid * 16;
  const float* __restrict__ xr = X + (size_t)(rt + l15) * DIN + kc * 8;
  const unsigned short* __restrict__ wb = WTb + (size_t)l15 * DIN + kc * 8;
  f32x4 acc0 = {0.f, 0.f, 0.f, 0.f};
  f32x4 acc1 = acc0, acc2 = acc0, acc3 = acc0;
#pragma unroll
  for (int ks = 0; ks < 8; ++ks) {
    const f32x4 x0 = *(const f32x4*)(xr + ks * 32);
    const f32x4 x1 = *(const f32x4*)(xr + ks * 32 + 4);
    short8 af;
    ((unsigned*)&af)[0] = pk2bf(x0[0], x0[1]);
    ((unsigned*)&af)[1] = pk2bf(x0[2], x0[3]);
    ((unsigned*)&af)[2] = pk2bf(x1[0], x1[1]);
    ((unsigned*)&af)[3] = pk2bf(x1[2], x1[3]);
    const short8 b0 = *(const short8*)(wb + ks * 32);
    const short8 b1 = *(const short8*)(wb + 16 * DIN + ks * 32);
    const short8 b2 = *(const short8*)(wb + 32 * DIN + ks * 32);
    const short8 b3 = *(const short8*)(wb + 48 * DIN + ks * 32);
    acc0 = __builtin_amdgcn_mfma_f32_16x16x32_bf16(af, b0, acc0, 0, 0, 0);
    acc1 = __builtin_amdgcn_mfma_f32_16x16x32_bf16(af, b1, acc1, 0, 0, 0);
    acc2 = __builtin_amdgcn_mfma_f32_16x16x32_bf16(af, b2, acc2, 0, 0, 0);
    acc3 = __builtin_amdgcn_mfma_f32_16x16x32_bf16(af, b3, acc3, 0, 0, 0);
  }
  const float as0 = A[l15], as1 = A[16 + l15], as2 = A[32 + l15],
              as3 = A[48 + l15];
  const float ad0 = A[64 + l15], ad1 = A[80 + l15], ad2 = A[96 + l15],
              ad3 = A[112 + l15];
  float dm = -1e30f;
#pragma unroll
  for (int v = 0; v < 4; ++v) {
    float sv = acc0[v] * as0 + acc1[v] * as1 + acc2[v] * as2 + acc3[v] * as3;
    float dv = acc0[v] * ad0 + acc1[v] * ad1 + acc2[v] * ad2 + acc3[v] * ad3;
#pragma unroll
    for (int m = 1; m < 16; m <<= 1) {
      sv += __shfl_xor(sv, m);
      dv += __shfl_xor(dv, m);
    }
    if (l15 == 0) {
      src[rt + kc * 4 + v] = sv;
      dst[rt + kc * 4 + v] = dv;
    }
    dm = fmaxf(dm, dv);
  }
  dm = fmaxf(dm, __shfl_xor(dm, 16));
  dm = fmaxf(dm, __shfl_xor(dm, 32));
  if (lane == 0) dmax_arr[blockIdx.x * 4 + wid] = dm;
  // HTt[jb][n][l15][jin] = bf16(h[jb*32+jin][n*16+l15])
  unsigned short* __restrict__ hs =
      HTt + (size_t)(rt >> 5) * 2048 + l15 * 32 + (rt & 16) + kc * 4;
  *(unsigned*)(hs + 0 * 512) = pk2bf(acc0[0], acc0[1]);
  *(unsigned*)(hs + 0 * 512 + 2) = pk2bf(acc0[2], acc0[3]);
  *(unsigned*)(hs + 1 * 512) = pk2bf(acc1[0], acc1[1]);
  *(unsigned*)(hs + 1 * 512 + 2) = pk2bf(acc1[2], acc1[3]);
  *(unsigned*)(hs + 2 * 512) = pk2bf(acc2[0], acc2[1]);
  *(unsigned*)(hs + 2 * 512 + 2) = pk2bf(acc2[2], acc2[3]);
  *(unsigned*)(hs + 3 * 512) = pk2bf(acc3[0], acc3[1]);
  *(unsigned*)(hs + 3 * 512 + 2) = pk2bf(acc3[2], acc3[3]);
}

// Fused adj-stream + masked-softmax-numerator @ H via MFMA; 32 rows/wave.
// 2 quarters of 256 j per chunk; quarter order staggered; bf16 partials.
__global__ __launch_bounds__(256) void k_att(
    const int* __restrict__ adj, const float* __restrict__ src,
    const float* __restrict__ dst, const float* __restrict__ dmax_arr,
    const unsigned short* __restrict__ HTt, unsigned short* __restrict__ pacc,
    float* __restrict__ ps) {
  __shared__ float E1s[CHJ], E2s[CHJ];
  __shared__ float dsm[4];
  __shared__ unsigned short Hs[16384];  // 32 KB: [8 s][4 n][64 lane][8]
  const int tid = threadIdx.x;
  const int wid = tid >> 6, lane = tid & 63;
  const int l15 = lane & 15, kc = lane >> 4;
  const int rowtile = blockIdx.x * 128 + wid * 32;
  const int c = blockIdx.y;
  const int cbase = c * CHJ;
  {
    const float2 dv2 = *(const float2*)(dst + cbase + tid * 2);
    E1s[tid * 2] = __expf(dv2.x);
    E1s[tid * 2 + 1] = __expf(dv2.y);
    E2s[tid * 2] = __expf(0.2f * dv2.x);
    E2s[tid * 2 + 1] = __expf(0.2f * dv2.y);
    float dm0 = fmaxf(dmax_arr[tid], dmax_arr[tid + 256]);
#pragma unroll
    for (int m = 1; m < 64; m <<= 1) dm0 = fmaxf(dm0, __shfl_xor(dm0, m));
    if (lane == 0) dsm[wid] = dm0;
  }
  __syncthreads();
  const float dmx = fmaxf(fmaxf(dsm[0], dsm[1]), fmaxf(dsm[2], dsm[3]));
  const int arA = rowtile + l15, arB = arA + 16;
  const float sA = src[arA], sB = src[arB];
  const float eA = sA + dmx, eB = sB + dmx;
  const float miA = fmaxf(eA, 0.2f * eA), miB = fmaxf(eB, 0.2f * eB);
  const float cA1 = __expf(sA - miA), cA2 = __expf(0.2f * sA - miA);
  const float cB1 = __expf(sB - miB), cB2 = __expf(0.2f * sB - miB);
  f32x4 aA0 = {0.f, 0.f, 0.f, 0.f};
  f32x4 aA1 = aA0, aA2 = aA0, aA3 = aA0;
  f32x4 aB0 = aA0, aB1 = aA0, aB2 = aA0, aB3 = aA0;
  float sacA = 0.f, sacB = 0.f;
  // staging source: permute [s][n][l15][kc*8] -> lds [s][n][lane][8]
  const unsigned short* __restrict__ Hsrc =
      HTt + (size_t)(cbase >> 5) * 2048 + (tid >> 6) * 512 + (tid & 15) * 32 +
      ((tid >> 4) & 3) * 8;
  const int HsW = (tid >> 6) * 512 + (tid & 63) * 8;  // dst short idx (per s)
  const int hfirst = (blockIdx.x + blockIdx.y) & 1;   // 2-phase stagger
#pragma unroll
  for (int hh = 0; hh < 2; ++hh) {
    const int h = hfirst ^ hh;
    // ---- inline pack of this wave's 32 rows for this 256-j quarter ----
    unsigned loA[4], hiA[4], loB[4], hiB[4];
    {
      unsigned long long wA64[4] = {0ull, 0ull, 0ull, 0ull};
      unsigned long long wB64[4] = {0ull, 0ull, 0ull, 0ull};
      const int* __restrict__ ab =
          adj + (size_t)rowtile * NN + cbase + h * 256 + lane * 4;
#pragma unroll
      for (int g = 0; g < 4; ++g) {
        i32x4 v[8];
#pragma unroll
        for (int r8 = 0; r8 < 8; ++r8)
          v[r8] = *(const i32x4*)(ab + (size_t)(g * 8 + r8) * NN);
#pragma unroll
        for (int r8 = 0; r8 < 8; ++r8) {
          const int rr = g * 8 + r8;
          const unsigned long long b0 = __ballot(v[r8][0] > 0);
          const unsigned long long b1 = __ballot(v[r8][1] > 0);
          const unsigned long long b2 = __ballot(v[r8][2] > 0);
          const unsigned long long b3 = __ballot(v[r8][3] > 0);
          if (rr < 16) {
            const bool isA = (l15 == rr);
            wA64[0] = isA ? b0 : wA64[0];
            wA64[1] = isA ? b1 : wA64[1];
            wA64[2] = isA ? b2 : wA64[2];
            wA64[3] = isA ? b3 : wA64[3];
          } else {
            const bool isB = (l15 == rr - 16);
            wB64[0] = isB ? b0 : wB64[0];
            wB64[1] = isB ? b1 : wB64[1];
            wB64[2] = isB ? b2 : wB64[2];
            wB64[3] = isB ? b3 : wB64[3];
          }
        }
      }
#pragma unroll
      for (int m = 0; m < 4; ++m) {
        const unsigned long long shA = wA64[m] >> (kc * 2);
        const unsigned long long shB = wB64[m] >> (kc * 2);
        loA[m] = (unsigned)shA;
        hiA[m] = (unsigned)(shA >> 32);
        loB[m] = (unsigned)shB;
        hiB[m] = (unsigned)(shB >> 32);
      }
    }
    if (hh) __syncthreads();  // protect Hs before overwrite
    // stage 32KB quarter: s_local 0..7; thread copies one short8 per s_local
#pragma unroll
    for (int it = 0; it < 8; ++it) {
      const short8 v = *(const short8*)(Hsrc + (h * 8 + it) * 2048);
      *(short8*)(Hs + it * 2048 + HsW) = v;
    }
    __syncthreads();
#pragma unroll
    for (int q = 0; q < 2; ++q) {
#pragma unroll 2
      for (int s4 = 0; s4 < 4; ++s4) {
        const int sl = q * 4 + s4;  // s_local in quarter
        const int jr = (h * 8 + sl) * 32 + kc * 8;
        const f32x4 e1a = *(const f32x4*)&E1s[jr];
        const f32x4 e1b = *(const f32x4*)&E1s[jr + 4];
        const f32x4 e2a = *(const f32x4*)&E2s[jr];
        const f32x4 e2b = *(const f32x4*)&E2s[jr + 4];
        float pvA[8], pvB[8];
#pragma unroll
        for (int e = 0; e < 8; ++e) {
          const float E1v = (e < 4) ? e1a[e & 3] : e1b[e & 3];
          const float E2v = (e < 4) ? e2a[e & 3] : e2b[e & 3];
          const unsigned bsh = s4 * 8 + (e >> 2);
          const unsigned wa = q ? hiA[e & 3] : loA[e & 3];
          const unsigned wb2 = q ? hiB[e & 3] : loB[e & 3];
          float pA = fmaxf(cA1 * E1v, cA2 * E2v);
          float pB = fmaxf(cB1 * E1v, cB2 * E2v);
          pA = ((wa >> bsh) & 1u) ? pA : 0.f;
          pB = ((wb2 >> bsh) & 1u) ? pB : 0.f;
          sacA += pA;
          sacB += pB;
          pvA[e] = pA;
          pvB[e] = pB;
        }
        short8 afA, afB;
        ((unsigned*)&afA)[0] = cvtpk(pvA[0], pvA[1]);
        ((unsigned*)&afA)[1] = cvtpk(pvA[2], pvA[3]);
        ((unsigned*)&afA)[2] = cvtpk(pvA[4], pvA[5]);
        ((unsigned*)&afA)[3] = cvtpk(pvA[6], pvA[7]);
        ((unsigned*)&afB)[0] = cvtpk(pvB[0], pvB[1]);
        ((unsigned*)&afB)[1] = cvtpk(pvB[2], pvB[3]);
        ((unsigned*)&afB)[2] = cvtpk(pvB[4], pvB[5]);
        ((unsigned*)&afB)[3] = cvtpk(pvB[6], pvB[7]);
        const unsigned short* hj = Hs + sl * 2048 + lane * 8;
        const short8 bf0 = *(const short8*)(hj);
        const short8 bf1 = *(const short8*)(hj + 512);
        const short8 bf2 = *(const short8*)(hj + 1024);
        const short8 bf3 = *(const short8*)(hj + 1536);
        aA0 = __builtin_amdgcn_mfma_f32_16x16x32_bf16(afA, bf0, aA0, 0, 0, 0);
        aB0 = __builtin_amdgcn_mfma_f32_16x16x32_bf16(afB, bf0, aB0, 0, 0, 0);
        aA1 = __builtin_amdgcn_mfma_f32_16x16x32_bf16(afA, bf1, aA1, 0, 0, 0);
        aB1 = __builtin_amdgcn_mfma_f32_16x16x32_bf16(afB, bf1, aB1, 0, 0, 0);
        aA2 = __builtin_amdgcn_mfma_f32_16x16x32_bf16(afA, bf2, aA2, 0, 0, 0);
        aB2 = __builtin_amdgcn_mfma_f32_16x16x32_bf16(afB, bf2, aB2, 0, 0, 0);
        aA3 = __builtin_amdgcn_mfma_f32_16x16x32_bf16(afA, bf3, aA3, 0, 0, 0);
        aB3 = __builtin_amdgcn_mfma_f32_16x16x32_bf16(afB, bf3, aB3, 0, 0, 0);
      }
    }
  }
  float stA = sacA, stB = sacB;
  stA += __shfl_xor(stA, 16);
  stA += __shfl_xor(stA, 32);
  stB += __shfl_xor(stB, 16);
  stB += __shfl_xor(stB, 32);
  if (lane < 16) {
    ps[(size_t)c * NN + arA] = stA;
    ps[(size_t)c * NN + arB] = stB;
  }
  const int orA = rowtile + kc * 4;  // C/D: col=lane&15, row=kc*4+v
  unsigned short* __restrict__ pbA =
      pacc + ((size_t)c * NN + orA) * DOUT + l15;
  unsigned short* __restrict__ pbB = pbA + (size_t)16 * DOUT;
#pragma unroll
  for (int v = 0; v < 4; ++v) {
    pbA[(size_t)v * DOUT + 0] = f2bf(aA0[v]);
    pbA[(size_t)v * DOUT + 16] = f2bf(aA1[v]);
    pbA[(size_t)v * DOUT + 32] = f2bf(aA2[v]);
    pbA[(size_t)v * DOUT + 48] = f2bf(aA3[v]);
    pbB[(size_t)v * DOUT + 0] = f2bf(aB0[v]);
    pbB[(size_t)v * DOUT + 16] = f2bf(aB1[v]);
    pbB[(size_t)v * DOUT + 32] = f2bf(aB2[v]);
    pbB[(size_t)v * DOUT + 48] = f2bf(aB3[v]);
  }
}

__global__ __launch_bounds__(256) void k_fin(
    const unsigned short* __restrict__ pacc, const float* __restrict__ ps,
    float* __restrict__ out) {
  const int idx4 = blockIdx.x * 256 + threadIdx.x;  // group-of-4 index
  const int i = idx4 >> 4;
  float ss = 0.f;
  f32x4 as = {0.f, 0.f, 0.f, 0.f};
  const u16x4* __restrict__ p4 = (const u16x4*)pacc;
#pragma unroll
  for (int c = 0; c < NCH; ++c) {
    ss += ps[(size_t)c * NN + i];
    const u16x4 v = p4[(size_t)c * (NN * DOUT / 4) + idx4];
    as[0] += bf2f(v[0]);
    as[1] += bf2f(v[1]);
    as[2] += bf2f(v[2]);
    as[3] += bf2f(v[3]);
  }
  const float inv = 1.f / ss;
  f32x4 o;
#pragma unroll
  for (int e = 0; e < 4; ++e) {
    const float v = as[e] * inv;
    o[e] = v > 0.f ? v : (__expf(v) - 1.f);
  }
  *(f32x4*)(out + (size_t)idx4 * 4) = o;
}

extern "C" void kernel_launch(void* const* d_in, const int* in_sizes, int n_in,
                              void* d_out, int out_size, void* d_ws,
                              size_t ws_size, hipStream_t stream) {
  const float* X = (const float*)d_in[0];
  const int* adj = (const int*)d_in[1];
  const float* W = (const float*)d_in[2];
  const float* A = (const float*)d_in[3];
  float* out = (float*)d_out;
  char* ws = (char*)d_ws;
  float* src = (float*)(ws);                                   // 32 KB
  float* dst = (float*)(ws + (32u << 10));                     // 32 KB
  float* dmax_arr = (float*)(ws + (64u << 10));                // 2 KB
  unsigned short* WTb = (unsigned short*)(ws + (128u << 10));  // 32 KB
  unsigned short* HTt = (unsigned short*)(ws + (256u << 10));  // 1 MB
  unsigned short* pacc = (unsigned short*)(ws + (16u << 20));  // NCH*1 MB
  float* ps = (float*)(ws + (16u << 20) +
                       (size_t)NCH * NN * DOUT * sizeof(unsigned short));
  k_prep<<<64, 256, 0, stream>>>(W, WTb);
  k_hw<<<NN / 64, 256, 0, stream>>>(X, WTb, A, src, dst, dmax_arr, HTt);
  k_att<<<dim3(NN / 128, NCH), 256, 0, stream>>>(adj, src, dst, dmax_arr, HTt,
                                                 pacc, ps);
  k_fin<<<NN * DOUT / 1024, 256, 0, stream>>>(pacc, ps, out);
}

// Round 21
// 66.504 us; speedup vs baseline: 2.0136x; 1.0884x over previous
//
#include <hip/hip_runtime.h>
#include <hip/hip_bf16.h>

#define NN 8192
#define DIN 256
#define DOUT 64
#define NCH 16
#define CHJ (NN / NCH)  // 512
#define WLS 264  // padded LDS stride for W^T rows

typedef __attribute__((ext_vector_type(4))) float f32x4;
typedef __attribute__((ext_vector_type(4))) int i32x4;
typedef __attribute__((ext_vector_type(8))) short short8;
typedef __attribute__((ext_vector_type(4))) unsigned short u16x4;

__device__ __forceinline__ unsigned short f2bf(float f) {
  unsigned u = __float_as_uint(f);
  u += 0x7fffu + ((u >> 16) & 1u);
  return (unsigned short)(u >> 16);
}
__device__ __forceinline__ unsigned pk2bf(float lo, float hi) {
  return (unsigned)f2bf(lo) | ((unsigned)f2bf(hi) << 16);
}
__device__ __forceinline__ float bf2f(unsigned short s) {
  return __uint_as_float((unsigned)s << 16);
}
__device__ __forceinline__ unsigned cvtpk(float lo, float hi) {
  unsigned r;
  asm("v_cvt_pk_bf16_f32 %0, %1, %2" : "=v"(r) : "v"(lo), "v"(hi));
  return r;
}

// h = X@W via MFMA -> src/dst/dmax_arr/HTt. grid 256 x 128 (2 waves, 32 rows).
// W transposed to bf16 in LDS per block (no prep kernel).
__global__ __launch_bounds__(128) void k_hw(
    const float* __restrict__ X, const float* __restrict__ W,
    const float* __restrict__ A, float* __restrict__ src,
    float* __restrict__ dst, float* __restrict__ dmax_arr,
    unsigned short* __restrict__ HTt) {
  __shared__ unsigned short Wl[64 * WLS];  // Wl[d*WLS + k] = bf16(W[k][d])
  const int tid = threadIdx.x;
  const int wid = tid >> 6, lane = tid & 63;
  const int l15 = lane & 15, kc = lane >> 4;
#pragma unroll
  for (int half = 0; half < 2; ++half) {
    const int k = tid + half * 128;
    const f32x4* __restrict__ wr = (const f32x4*)(W + (size_t)k * DOUT);
#pragma unroll
    for (int i = 0; i < 16; ++i) {
      const f32x4 v = wr[i];
#pragma unroll
      for (int e = 0; e < 4; ++e) Wl[(i * 4 + e) * WLS + k] = f2bf(v[e]);
    }
  }
  __syncthreads();
  const int rt = blockIdx.x * 32 + wid * 16;
  const float* __restrict__ xr = X + (size_t)(rt + l15) * DIN + kc * 8;
  const unsigned short* __restrict__ wb = Wl + (size_t)l15 * WLS + kc * 8;
  f32x4 acc0 = {0.f, 0.f, 0.f, 0.f};
  f32x4 acc1 = acc0, acc2 = acc0, acc3 = acc0;
#pragma unroll
  for (int ks = 0; ks < 8; ++ks) {
    const f32x4 x0 = *(const f32x4*)(xr + ks * 32);
    const f32x4 x1 = *(const f32x4*)(xr + ks * 32 + 4);
    short8 af;
    ((unsigned*)&af)[0] = pk2bf(x0[0], x0[1]);
    ((unsigned*)&af)[1] = pk2bf(x0[2], x0[3]);
    ((unsigned*)&af)[2] = pk2bf(x1[0], x1[1]);
    ((unsigned*)&af)[3] = pk2bf(x1[2], x1[3]);
    const short8 b0 = *(const short8*)(wb + ks * 32);
    const short8 b1 = *(const short8*)(wb + 16 * WLS + ks * 32);
    const short8 b2 = *(const short8*)(wb + 32 * WLS + ks * 32);
    const short8 b3 = *(const short8*)(wb + 48 * WLS + ks * 32);
    acc0 = __builtin_amdgcn_mfma_f32_16x16x32_bf16(af, b0, acc0, 0, 0, 0);
    acc1 = __builtin_amdgcn_mfma_f32_16x16x32_bf16(af, b1, acc1, 0, 0, 0);
    acc2 = __builtin_amdgcn_mfma_f32_16x16x32_bf16(af, b2, acc2, 0, 0, 0);
    acc3 = __builtin_amdgcn_mfma_f32_16x16x32_bf16(af, b3, acc3, 0, 0, 0);
  }
  const float as0 = A[l15], as1 = A[16 + l15], as2 = A[32 + l15],
              as3 = A[48 + l15];
  const float ad0 = A[64 + l15], ad1 = A[80 + l15], ad2 = A[96 + l15],
              ad3 = A[112 + l15];
  float dm = -1e30f;
#pragma unroll
  for (int v = 0; v < 4; ++v) {
    float sv = acc0[v] * as0 + acc1[v] * as1 + acc2[v] * as2 + acc3[v] * as3;
    float dv = acc0[v] * ad0 + acc1[v] * ad1 + acc2[v] * ad2 + acc3[v] * ad3;
#pragma unroll
    for (int m = 1; m < 16; m <<= 1) {
      sv += __shfl_xor(sv, m);
      dv += __shfl_xor(dv, m);
    }
    if (l15 == 0) {
      src[rt + kc * 4 + v] = sv;
      dst[rt + kc * 4 + v] = dv;
    }
    dm = fmaxf(dm, dv);
  }
  dm = fmaxf(dm, __shfl_xor(dm, 16));
  dm = fmaxf(dm, __shfl_xor(dm, 32));
  if (lane == 0) dmax_arr[blockIdx.x * 2 + wid] = dm;
  // HTt[jb][n][l15][jin] = bf16(h[jb*32+jin][n*16+l15])
  unsigned short* __restrict__ hs =
      HTt + (size_t)(rt >> 5) * 2048 + l15 * 32 + (rt & 16) + kc * 4;
  *(unsigned*)(hs + 0 * 512) = pk2bf(acc0[0], acc0[1]);
  *(unsigned*)(hs + 0 * 512 + 2) = pk2bf(acc0[2], acc0[3]);
  *(unsigned*)(hs + 1 * 512) = pk2bf(acc1[0], acc1[1]);
  *(unsigned*)(hs + 1 * 512 + 2) = pk2bf(acc1[2], acc1[3]);
  *(unsigned*)(hs + 2 * 512) = pk2bf(acc2[0], acc2[1]);
  *(unsigned*)(hs + 2 * 512 + 2) = pk2bf(acc2[2], acc2[3]);
  *(unsigned*)(hs + 3 * 512) = pk2bf(acc3[0], acc3[1]);
  *(unsigned*)(hs + 3 * 512 + 2) = pk2bf(acc3[2], acc3[3]);
}

// Fused adj-stream + masked-softmax-numerator @ H via MFMA; 32 rows/wave.
// 2 quarters of 256 j per chunk; quarter order staggered; bf16 partials.
__global__ __launch_bounds__(256) void k_att(
    const int* __restrict__ adj, const float* __restrict__ src,
    const float* __restrict__ dst, const float* __restrict__ dmax_arr,
    const unsigned short* __restrict__ HTt, unsigned short* __restrict__ pacc,
    float* __restrict__ ps) {
  __shared__ float E1s[CHJ], E2s[CHJ];
  __shared__ float dsm[4];
  __shared__ unsigned short Hs[16384];  // 32 KB: [8 s][4 n][64 lane][8]
  const int tid = threadIdx.x;
  const int wid = tid >> 6, lane = tid & 63;
  const int l15 = lane & 15, kc = lane >> 4;
  const int rowtile = blockIdx.x * 128 + wid * 32;
  const int c = blockIdx.y;
  const int cbase = c * CHJ;
  {
    const float2 dv2 = *(const float2*)(dst + cbase + tid * 2);
    E1s[tid * 2] = __expf(dv2.x);
    E1s[tid * 2 + 1] = __expf(dv2.y);
    E2s[tid * 2] = __expf(0.2f * dv2.x);
    E2s[tid * 2 + 1] = __expf(0.2f * dv2.y);
    float dm0 = fmaxf(dmax_arr[tid], dmax_arr[tid + 256]);
#pragma unroll
    for (int m = 1; m < 64; m <<= 1) dm0 = fmaxf(dm0, __shfl_xor(dm0, m));
    if (lane == 0) dsm[wid] = dm0;
  }
  __syncthreads();
  const float dmx = fmaxf(fmaxf(dsm[0], dsm[1]), fmaxf(dsm[2], dsm[3]));
  const int arA = rowtile + l15, arB = arA + 16;
  const float sA = src[arA], sB = src[arB];
  const float eA = sA + dmx, eB = sB + dmx;
  const float miA = fmaxf(eA, 0.2f * eA), miB = fmaxf(eB, 0.2f * eB);
  const float cA1 = __expf(sA - miA), cA2 = __expf(0.2f * sA - miA);
  const float cB1 = __expf(sB - miB), cB2 = __expf(0.2f * sB - miB);
  f32x4 aA0 = {0.f, 0.f, 0.f, 0.f};
  f32x4 aA1 = aA0, aA2 = aA0, aA3 = aA0;
  f32x4 aB0 = aA0, aB1 = aA0, aB2 = aA0, aB3 = aA0;
  float sacA = 0.f, sacB = 0.f;
  // staging source: permute [s][n][l15][kc*8] -> lds [s][n][lane][8]
  const unsigned short* __restrict__ Hsrc =
      HTt + (size_t)(cbase >> 5) * 2048 + (tid >> 6) * 512 + (tid & 15) * 32 +
      ((tid >> 4) & 3) * 8;
  const int HsW = (tid >> 6) * 512 + (tid & 63) * 8;  // dst short idx (per s)
  const int hfirst = (blockIdx.x + blockIdx.y) & 1;   // 2-phase stagger
#pragma unroll
  for (int hh = 0; hh < 2; ++hh) {
    const int h = hfirst ^ hh;
    // ---- inline pack of this wave's 32 rows for this 256-j quarter ----
    unsigned loA[4], hiA[4], loB[4], hiB[4];
    {
      unsigned long long wA64[4] = {0ull, 0ull, 0ull, 0ull};
      unsigned long long wB64[4] = {0ull, 0ull, 0ull, 0ull};
      const int* __restrict__ ab =
          adj + (size_t)rowtile * NN + cbase + h * 256 + lane * 4;
#pragma unroll
      for (int g = 0; g < 4; ++g) {
        i32x4 v[8];
#pragma unroll
        for (int r8 = 0; r8 < 8; ++r8)
          v[r8] = *(const i32x4*)(ab + (size_t)(g * 8 + r8) * NN);
#pragma unroll
        for (int r8 = 0; r8 < 8; ++r8) {
          const int rr = g * 8 + r8;
          const unsigned long long b0 = __ballot(v[r8][0] > 0);
          const unsigned long long b1 = __ballot(v[r8][1] > 0);
          const unsigned long long b2 = __ballot(v[r8][2] > 0);
          const unsigned long long b3 = __ballot(v[r8][3] > 0);
          if (rr < 16) {
            const bool isA = (l15 == rr);
            wA64[0] = isA ? b0 : wA64[0];
            wA64[1] = isA ? b1 : wA64[1];
            wA64[2] = isA ? b2 : wA64[2];
            wA64[3] = isA ? b3 : wA64[3];
          } else {
            const bool isB = (l15 == rr - 16);
            wB64[0] = isB ? b0 : wB64[0];
            wB64[1] = isB ? b1 : wB64[1];
            wB64[2] = isB ? b2 : wB64[2];
            wB64[3] = isB ? b3 : wB64[3];
          }
        }
      }
#pragma unroll
      for (int m = 0; m < 4; ++m) {
        const unsigned long long shA = wA64[m] >> (kc * 2);
        const unsigned long long shB = wB64[m] >> (kc * 2);
        loA[m] = (unsigned)shA;
        hiA[m] = (unsigned)(shA >> 32);
        loB[m] = (unsigned)shB;
        hiB[m] = (unsigned)(shB >> 32);
      }
    }
    if (hh) __syncthreads();  // protect Hs before overwrite
    // stage 32KB quarter: s_local 0..7; thread copies one short8 per s_local
#pragma unroll
    for (int it = 0; it < 8; ++it) {
      const short8 v = *(const short8*)(Hsrc + (h * 8 + it) * 2048);
      *(short8*)(Hs + it * 2048 + HsW) = v;
    }
    __syncthreads();
#pragma unroll
    for (int q = 0; q < 2; ++q) {
#pragma unroll 2
      for (int s4 = 0; s4 < 4; ++s4) {
        const int sl = q * 4 + s4;  // s_local in quarter
        const int jr = (h * 8 + sl) * 32 + kc * 8;
        const f32x4 e1a = *(const f32x4*)&E1s[jr];
        const f32x4 e1b = *(const f32x4*)&E1s[jr + 4];
        const f32x4 e2a = *(const f32x4*)&E2s[jr];
        const f32x4 e2b = *(const f32x4*)&E2s[jr + 4];
        float pvA[8], pvB[8];
#pragma unroll
        for (int e = 0; e < 8; ++e) {
          const float E1v = (e < 4) ? e1a[e & 3] : e1b[e & 3];
          const float E2v = (e < 4) ? e2a[e & 3] : e2b[e & 3];
          const unsigned bsh = s4 * 8 + (e >> 2);
          const unsigned wa = q ? hiA[e & 3] : loA[e & 3];
          const unsigned wb2 = q ? hiB[e & 3] : loB[e & 3];
          float pA = fmaxf(cA1 * E1v, cA2 * E2v);
          float pB = fmaxf(cB1 * E1v, cB2 * E2v);
          pA = ((wa >> bsh) & 1u) ? pA : 0.f;
          pB = ((wb2 >> bsh) & 1u) ? pB : 0.f;
          sacA += pA;
          sacB += pB;
          pvA[e] = pA;
          pvB[e] = pB;
        }
        short8 afA, afB;
        ((unsigned*)&afA)[0] = cvtpk(pvA[0], pvA[1]);
        ((unsigned*)&afA)[1] = cvtpk(pvA[2], pvA[3]);
        ((unsigned*)&afA)[2] = cvtpk(pvA[4], pvA[5]);
        ((unsigned*)&afA)[3] = cvtpk(pvA[6], pvA[7]);
        ((unsigned*)&afB)[0] = cvtpk(pvB[0], pvB[1]);
        ((unsigned*)&afB)[1] = cvtpk(pvB[2], pvB[3]);
        ((unsigned*)&afB)[2] = cvtpk(pvB[4], pvB[5]);
        ((unsigned*)&afB)[3] = cvtpk(pvB[6], pvB[7]);
        const unsigned short* hj = Hs + sl * 2048 + lane * 8;
        const short8 bf0 = *(const short8*)(hj);
        const short8 bf1 = *(const short8*)(hj + 512);
        const short8 bf2 = *(const short8*)(hj + 1024);
        const short8 bf3 = *(const short8*)(hj + 1536);
        aA0 = __builtin_amdgcn_mfma_f32_16x16x32_bf16(afA, bf0, aA0, 0, 0, 0);
        aB0 = __builtin_amdgcn_mfma_f32_16x16x32_bf16(afB, bf0, aB0, 0, 0, 0);
        aA1 = __builtin_amdgcn_mfma_f32_16x16x32_bf16(afA, bf1, aA1, 0, 0, 0);
        aB1 = __builtin_amdgcn_mfma_f32_16x16x32_bf16(afB, bf1, aB1, 0, 0, 0);
        aA2 = __builtin_amdgcn_mfma_f32_16x16x32_bf16(afA, bf2, aA2, 0, 0, 0);
        aB2 = __builtin_amdgcn_mfma_f32_16x16x32_bf16(afB, bf2, aB2, 0, 0, 0);
        aA3 = __builtin_amdgcn_mfma_f32_16x16x32_bf16(afA, bf3, aA3, 0, 0, 0);
        aB3 = __builtin_amdgcn_mfma_f32_16x16x32_bf16(afB, bf3, aB3, 0, 0, 0);
      }
    }
  }
  float stA = sacA, stB = sacB;
  stA += __shfl_xor(stA, 16);
  stA += __shfl_xor(stA, 32);
  stB += __shfl_xor(stB, 16);
  stB += __shfl_xor(stB, 32);
  if (lane < 16) {
    ps[(size_t)c * NN + arA] = stA;
    ps[(size_t)c * NN + arB] = stB;
  }
  const int orA = rowtile + kc * 4;  // C/D: col=lane&15, row=kc*4+v
  unsigned short* __restrict__ pbA =
      pacc + ((size_t)c * NN + orA) * DOUT + l15;
  unsigned short* __restrict__ pbB = pbA + (size_t)16 * DOUT;
#pragma unroll
  for (int v = 0; v < 4; ++v) {
    pbA[(size_t)v * DOUT + 0] = f2bf(aA0[v]);
    pbA[(size_t)v * DOUT + 16] = f2bf(aA1[v]);
    pbA[(size_t)v * DOUT + 32] = f2bf(aA2[v]);
    pbA[(size_t)v * DOUT + 48] = f2bf(aA3[v]);
    pbB[(size_t)v * DOUT + 0] = f2bf(aB0[v]);
    pbB[(size_t)v * DOUT + 16] = f2bf(aB1[v]);
    pbB[(size_t)v * DOUT + 32] = f2bf(aB2[v]);
    pbB[(size_t)v * DOUT + 48] = f2bf(aB3[v]);
  }
}

__global__ __launch_bounds__(256) void k_fin(
    const unsigned short* __restrict__ pacc, const float* __restrict__ ps,
    float* __restrict__ out) {
  const int idx4 = blockIdx.x * 256 + threadIdx.x;  // group-of-4 index
  const int i = idx4 >> 4;
  float ss = 0.f;
  f32x4 as = {0.f, 0.f, 0.f, 0.f};
  const u16x4* __restrict__ p4 = (const u16x4*)pacc;
#pragma unroll
  for (int c = 0; c < NCH; ++c) {
    ss += ps[(size_t)c * NN + i];
    const u16x4 v = p4[(size_t)c * (NN * DOUT / 4) + idx4];
    as[0] += bf2f(v[0]);
    as[1] += bf2f(v[1]);
    as[2] += bf2f(v[2]);
    as[3] += bf2f(v[3]);
  }
  const float inv = 1.f / ss;
  f32x4 o;
#pragma unroll
  for (int e = 0; e < 4; ++e) {
    const float v = as[e] * inv;
    o[e] = v > 0.f ? v : (__expf(v) - 1.f);
  }
  *(f32x4*)(out + (size_t)idx4 * 4) = o;
}

extern "C" void kernel_launch(void* const* d_in, const int* in_sizes, int n_in,
                              void* d_out, int out_size, void* d_ws,
                              size_t ws_size, hipStream_t stream) {
  const float* X = (const float*)d_in[0];
  const int* adj = (const int*)d_in[1];
  const float* W = (const float*)d_in[2];
  const float* A = (const float*)d_in[3];
  float* out = (float*)d_out;
  char* ws = (char*)d_ws;
  float* src = (float*)(ws);                                   // 32 KB
  float* dst = (float*)(ws + (32u << 10));                     // 32 KB
  float* dmax_arr = (float*)(ws + (64u << 10));                // 2 KB
  unsigned short* HTt = (unsigned short*)(ws + (256u << 10));  // 1 MB
  unsigned short* pacc = (unsigned short*)(ws + (16u << 20));  // NCH*1 MB
  float* ps = (float*)(ws + (16u << 20) +
                       (size_t)NCH * NN * DOUT * sizeof(unsigned short));
  k_hw<<<NN / 32, 128, 0, stream>>>(X, W, A, src, dst, dmax_arr, HTt);
  k_att<<<dim3(NN / 128, NCH), 256, 0, stream>>>(adj, src, dst, dmax_arr, HTt,
                                                 pacc, ps);
  k_fin<<<NN * DOUT / 1024, 256, 0, stream>>>(pacc, ps, out);
}